// Round 5
// baseline (4338.948 us; speedup 1.0000x reference)
//
#include <hip/hip_runtime.h>

typedef __attribute__((ext_vector_type(8))) short short8v;
typedef __attribute__((ext_vector_type(4))) float f32x4;
typedef __attribute__((ext_vector_type(4))) float float4v;
typedef unsigned int u32;
typedef unsigned long long u64;

#define NT 512
#define SLOT 8192                        // shorts per ring slot (8 rows x 1024)
#define RING_TEAM ((size_t)(NT + 1) * SLOT)
#define CNT_T_STRIDE 16                  // u32 per step slot (64B line each)
#define CNT_TEAM_STRIDE (520 * 16)       // u32 per team
#define RED_S 65                         // floats per red slot (bank-conflict pad)

__device__ __forceinline__ short f2bf(float f) {
  union { float f; unsigned u; } c; c.f = f;
  unsigned r = (c.u + 0x7fffu + ((c.u >> 16) & 1u)) >> 16;
  return (short)r;
}

__device__ __forceinline__ short8v cvt8(float4v a, float4v b) {
  short8v s;
  s[0]=f2bf(a[0]); s[1]=f2bf(a[1]); s[2]=f2bf(a[2]); s[3]=f2bf(a[3]);
  s[4]=f2bf(b[0]); s[5]=f2bf(b[1]); s[6]=f2bf(b[2]); s[7]=f2bf(b[3]);
  return s;
}

// ---------------------------------------------------------------------------
// Batch-parallel GRU with round-0's PROVEN protocol, team-partitioned.
// 256 wgs x 512 thr (8 waves); 88KB dyn-LDS => 1 wg/CU. Team p = blockIdx&7
// owns batch rows 8p..+8; wg s = blockIdx>>3 owns h-cols 32s..+32.
// Waves 0-3: h-GEMM (gate g, K-half kh), U-frags in regs (128 VGPR), a8
//   chunked by 8 (no spills). Waves 4-7: x-GEMM from double-buffered LDS
//   (r4 pipeline: gload t+3 -> regs -> ds_write t+2).
// Handoff (r0-proven pieces only):
//   data:  producer agent-scope u64 stores (write-through to MALL);
//          consumers CACHED loads of write-once ring addresses (payload read
//          exactly once; entry acquire-fence kills cross-launch staleness).
//   signal: ONE counter per (team, step). Wave 4 does the whole epilogue
//          (4 vals/lane), publishes, vmcnt(0), lane0 atomicAdd(cnt[t+1]).
//          Consumers poll a single agent-scope address until ==32.
//          => poll traffic ~32x lower than r0's 32-line flag gather; no
//          sentinel memset; monotonic counters => no deadlock modes.
// ---------------------------------------------------------------------------
__global__ __launch_bounds__(512, 2) void gru_kernel(
    const float* __restrict__ h0, const float* __restrict__ Wh, const float* __restrict__ Wz,
    const float* __restrict__ Uh, const float* __restrict__ Uz, const float* __restrict__ bz,
    const float* __restrict__ Wout, const float* __restrict__ x,
    short* __restrict__ ring, u32* __restrict__ cnt, float* __restrict__ out)
{
  extern __shared__ char smem[];
  float* red  = (float*)smem;               // [2 par][8 wv][2 ct][4 reg] x 65 = 33,280 B
  short* xbuf = (short*)(smem + 33280);     // [2 buf][2 kh][64 kc][8 row][8 k] = 32 KB
  short* rp   = (short*)(smem + 33280 + 32768);  // wave-4 repack, 512 B

  __builtin_amdgcn_fence(__ATOMIC_ACQUIRE, "agent");   // kill cross-launch stale lines

  const int tid  = threadIdx.x;
  const int lane = tid & 63;
  const int wv   = tid >> 6;
  const int colL = lane & 15;
  const int rowA = lane & 7;
  const int quad = lane >> 4;
  const int kq   = quad * 8;
  const int p    = blockIdx.x & 7;
  const int s    = blockIdx.x >> 3;
  const int RB   = p * 8;
  const int JB   = s * 32;
  short* ringp = ring + (size_t)p * RING_TEAM;
  u32*   cntp  = cnt + p * CNT_TEAM_STRIDE;
  const bool isH = wv < 4;
  const int g    = (wv & 3) >> 1;     // gate: 0=z, 1=htilde
  const int kh   = wv & 1;            // K-half
  const int xw   = wv - 4;

  // ---- weights into registers: 16 kb x 2 col-tiles = 128 VGPR ----
  short8v bw[16][2];
  {
    const float* M = isH ? (g ? Uh : Uz) : (g ? Wh : Wz);
#pragma unroll
    for (int i = 0; i < 16; ++i)
#pragma unroll
      for (int j = 0; j < 2; ++j) {
        const float* mr = M + (size_t)(JB + j * 16 + colL) * 1024 + kh * 512 + i * 32 + kq;
        bw[i][j] = cvt8(*(const float4v*)mr, *(const float4v*)(mr + 4));
      }
  }

  // ---- x-wave state: tail out-mapping + staging prologue ----
  float4v gA[4], gB[4];
  int er = 0, ec = 0;
  if (!isH) {
    er = xw * 2 + (lane >> 5);
    ec = lane & 31;
#pragma unroll
    for (int b = 0; b < 2; ++b) {             // buf0 = x(0), buf1 = x(1)
      float4v ta[4], tb[4];
#pragma unroll
      for (int j = 0; j < 4; ++j) {
        const int so = xw * 2048 + j * 512 + lane * 8;
        const float* src = x + ((size_t)(RB + ((so >> 3) & 7)) * NT + b) * 1024
                         + (so >> 12) * 512 + ((so >> 6) & 63) * 8;
        ta[j] = *(const float4v*)src; tb[j] = *(const float4v*)(src + 4);
      }
#pragma unroll
      for (int j = 0; j < 4; ++j)
        *(short8v*)(xbuf + b * 8192 + xw * 2048 + j * 512 + lane * 8) = cvt8(ta[j], tb[j]);
    }
#pragma unroll
    for (int j = 0; j < 4; ++j) {             // issue x(2)
      const int so = xw * 2048 + j * 512 + lane * 8;
      const float* src = x + ((size_t)(RB + ((so >> 3) & 7)) * NT + 2) * 1024
                       + (so >> 12) * 512 + ((so >> 6) & 63) * 8;
      gA[j] = *(const float4v*)src; gB[j] = *(const float4v*)(src + 4);
    }
  }
  const int rg = er & 3, ctE = ec >> 4, lsrc = (er >> 2) * 16 + (ec & 15);

  // ---- wave-4 epilogue state: 4 h-values/lane (rows 2k+half, col ec4) ----
  float hl4[4] = {0.f, 0.f, 0.f, 0.f};
  float bzv = 0.f;
  int ec4 = 0, half4 = 0;
  if (wv == 4) {
    ec4 = lane & 31; half4 = lane >> 5;
    bzv = bz[JB + ec4];
#pragma unroll
    for (int k = 0; k < 4; ++k)
      hl4[k] = h0[(size_t)(RB + 2 * k + half4) * 1024 + JB + ec4];
  }
  __syncthreads();

  // =========================== RECURRENCE ==================================
  for (int t = 0; t < NT; ++t) {
    const int par = t & 1;
    f32x4 ac0 = {0.f,0.f,0.f,0.f}, ac1 = ac0;

    if (isH) {
      if (t == 0) {
        const float* hr0 = h0 + (size_t)(RB + rowA) * 1024 + kh * 512 + kq;
#pragma unroll
        for (int c2 = 0; c2 < 2; ++c2) {
          short8v a[8];
#pragma unroll
          for (int i = 0; i < 8; ++i)
            a[i] = cvt8(*(const float4v*)(hr0 + (c2 * 8 + i) * 32),
                        *(const float4v*)(hr0 + (c2 * 8 + i) * 32 + 4));
#pragma unroll
          for (int i = 0; i < 8; ++i) {
            ac0 = __builtin_amdgcn_mfma_f32_16x16x32_bf16(a[i], bw[c2*8+i][0], ac0, 0, 0, 0);
            ac1 = __builtin_amdgcn_mfma_f32_16x16x32_bf16(a[i], bw[c2*8+i][1], ac1, 0, 0, 0);
          }
        }
      } else {
        const u32* ca = cntp + t * CNT_T_STRIDE;
        for (;;) {
          u32 c = __hip_atomic_load(ca, __ATOMIC_RELAXED, __HIP_MEMORY_SCOPE_AGENT);
          if (c >= 32u) break;
          __builtin_amdgcn_s_sleep(1);
        }
        __asm__ volatile("" ::: "memory");        // keep data loads below poll exit
        const short* hr = ringp + (size_t)t * SLOT + rowA * 1024 + kh * 512 + kq;
#pragma unroll
        for (int c2 = 0; c2 < 2; ++c2) {
          short8v a[8];
#pragma unroll
          for (int i = 0; i < 8; ++i) a[i] = *(const short8v*)(hr + (c2 * 8 + i) * 32);
#pragma unroll
          for (int i = 0; i < 8; ++i) {
            ac0 = __builtin_amdgcn_mfma_f32_16x16x32_bf16(a[i], bw[c2*8+i][0], ac0, 0, 0, 0);
            ac1 = __builtin_amdgcn_mfma_f32_16x16x32_bf16(a[i], bw[c2*8+i][1], ac1, 0, 0, 0);
          }
        }
      }
    } else {
      const short* xb = xbuf + par * 8192 + kh * 4096 + quad * 64 + rowA * 8;
#pragma unroll
      for (int i = 0; i < 16; ++i) {
        short8v a = *(const short8v*)(xb + i * 256);
        ac0 = __builtin_amdgcn_mfma_f32_16x16x32_bf16(a, bw[i][0], ac0, 0, 0, 0);
        ac1 = __builtin_amdgcn_mfma_f32_16x16x32_bf16(a, bw[i][1], ac1, 0, 0, 0);
      }
    }

    // partials: slot = wv*8 + ct*4 + reg, stride-65 (conflict-free both ways)
    {
      float* rb = red + (size_t)(par * 64 + wv * 8) * RED_S + lane;
#pragma unroll
      for (int reg = 0; reg < 4; ++reg) {
        rb[reg * RED_S]       = ac0[reg];
        rb[(4 + reg) * RED_S] = ac1[reg];
      }
    }
    __syncthreads();

    if (wv == 4) {
      // full epilogue on one wave: reduce 8 slots x 4 values, gates, publish
      const float* rb0 = red + (size_t)(par * 64) * RED_S;
#pragma unroll
      for (int k = 0; k < 4; ++k) {
        const int e    = 2 * k + half4;
        const int base = (ec4 >> 4) * 4 + (e & 3);
        const int ls   = (e >> 2) * 16 + (ec4 & 15);
        float az = rb0[(0 * 8 + base) * RED_S + ls] + rb0[(1 * 8 + base) * RED_S + ls]
                 + rb0[(4 * 8 + base) * RED_S + ls] + rb0[(5 * 8 + base) * RED_S + ls];
        float ah = rb0[(2 * 8 + base) * RED_S + ls] + rb0[(3 * 8 + base) * RED_S + ls]
                 + rb0[(6 * 8 + base) * RED_S + ls] + rb0[(7 * 8 + base) * RED_S + ls];
        float z  = 1.f / (1.f + __expf(-(az + bzv)));
        float ht = 2.f / (1.f + __expf(-2.f * ah)) - 1.f;   // tanh, overflow-safe
        hl4[k] += z * (ht - hl4[k]);
        rp[e * 32 + ec4] = f2bf(hl4[k]);
      }
      __asm__ volatile("s_waitcnt lgkmcnt(0)" ::: "memory");
      __builtin_amdgcn_sched_barrier(0);
      // publish 512B: 64 lanes x 1 u64 agent store (write-through to MALL)
      {
        u64 val = ((const u64*)rp)[lane];
        u64* dst = (u64*)ringp + (size_t)(t + 1) * (SLOT / 4)
                 + (lane >> 3) * 256 + (JB >> 2) + (lane & 7);
        __hip_atomic_store(dst, val, __ATOMIC_RELAXED, __HIP_MEMORY_SCOPE_AGENT);
      }
      __asm__ volatile("s_waitcnt vmcnt(0)" ::: "memory");   // data in MALL before count
      if (lane == 0)
        __hip_atomic_fetch_add(cntp + (size_t)(t + 1) * CNT_T_STRIDE, 1u,
                               __ATOMIC_RELAXED, __HIP_MEMORY_SCOPE_AGENT);
    }

    if (!isH) {
      if (t + 2 < NT) {      // ds_write staged x(t+2) into buf[par] (read at t+2)
        short* wb = xbuf + par * 8192 + xw * 2048 + lane * 8;
#pragma unroll
        for (int j = 0; j < 4; ++j)
          *(short8v*)(wb + j * 512) = cvt8(gA[j], gB[j]);
      }
      if (t + 3 < NT) {      // issue gloads x(t+3)
#pragma unroll
        for (int j = 0; j < 4; ++j) {
          const int so = xw * 2048 + j * 512 + lane * 8;
          const float* src = x + ((size_t)(RB + ((so >> 3) & 7)) * NT + (t + 3)) * 1024
                           + (so >> 12) * 512 + ((so >> 6) & 63) * 8;
          gA[j] = *(const float4v*)src; gB[j] = *(const float4v*)(src + 4);
        }
      }
    }
  }

  // ======================= TAIL: out = hT @ Wout^T =========================
  {
    const int ctt = wv & 1, k8 = wv >> 1;   // 8 waves: (col-tile, K-quarter)
    short8v tw[8];
#pragma unroll
    for (int i = 0; i < 8; ++i) {
      const float* wr = Wout + (size_t)(JB + ctt * 16 + colL) * 1024 + k8 * 256 + i * 32 + kq;
      tw[i] = cvt8(*(const float4v*)wr, *(const float4v*)(wr + 4));
    }
    {
      const u32* ca = cntp + (size_t)NT * CNT_T_STRIDE;
      for (;;) {
        u32 c = __hip_atomic_load(ca, __ATOMIC_RELAXED, __HIP_MEMORY_SCOPE_AGENT);
        if (c >= 32u) break;
        __builtin_amdgcn_s_sleep(1);
      }
      __asm__ volatile("" ::: "memory");
    }
    const short* hrt = ringp + (size_t)NT * SLOT + rowA * 1024 + k8 * 256 + kq;
    f32x4 oc = {0.f,0.f,0.f,0.f};
#pragma unroll
    for (int i = 0; i < 8; ++i) {
      short8v a = *(const short8v*)(hrt + i * 32);
      oc = __builtin_amdgcn_mfma_f32_16x16x32_bf16(a, tw[i], oc, 0, 0, 0);
    }
    __syncthreads();          // last epilogue's red reads complete before reuse
    {
      float* rb = red + (size_t)(wv * 4) * RED_S + lane;
#pragma unroll
      for (int reg = 0; reg < 4; ++reg) rb[reg * RED_S] = oc[reg];
    }
    __syncthreads();
    if (!isH) {
      float o = 0.f;
#pragma unroll
      for (int q2 = 0; q2 < 4; ++q2)
        o += red[(size_t)((q2 * 2 + ctE) * 4 + rg) * RED_S + lsrc];
      out[(size_t)(RB + er) * 1024 + JB + ec] = o;
    }
  }
}

extern "C" void kernel_launch(void* const* d_in, const int* in_sizes, int n_in,
                              void* d_out, int out_size, void* d_ws, size_t ws_size,
                              hipStream_t stream) {
  const float* x    = (const float*)d_in[0];
  const float* h0   = (const float*)d_in[1];
  const float* Wh   = (const float*)d_in[2];
  const float* Wz   = (const float*)d_in[3];
  const float* Uh   = (const float*)d_in[5];
  const float* Uz   = (const float*)d_in[6];
  const float* bz   = (const float*)d_in[8];
  const float* Wout = (const float*)d_in[10];

  char* ws = (char*)d_ws;
  // layout: cnt [0, 320K) (8 teams x 520 steps x 64B) | ring [320K, +67.2MB)
  u32*   cnt  = (u32*)ws;
  short* ring = (short*)(ws + 327680);

  hipMemsetAsync(ws, 0, 327680, stream);   // counters only; NO ring memset needed

  hipFuncSetAttribute((const void*)gru_kernel,
                      hipFuncAttributeMaxDynamicSharedMemorySize, 90112);
  gru_kernel<<<256, 512, 90112, stream>>>(h0, Wh, Wz, Uh, Uz, bz, Wout, x,
                                          ring, cnt, (float*)d_out);
}